// Round 2
// baseline (202.725 us; speedup 1.0000x reference)
//
#include <hip/hip_runtime.h>

// Problem constants (B,C,H,W,K) = (32,192,56,56,7)
#define BB 32
#define CC 192
#define HH 56
#define WW 56
#define KS 7
#define HW 3136        // 56*56
#define KK 49          // 7*7
#define CKK 9408       // C*K*K
#define PL 8           // pool window
#define NCELL (BB * CC * KK)   // 301056 = 1176*256 exactly
#define NBC (BB * CC)          // 6144

// ---------------------------------------------------------------------------
// Kernel 1: avg pool 56x56 -> 7x7 + per-sample LN0 stats via wave atomics.
// 64 | 9408, so a 64-lane wave never straddles two samples.
// ---------------------------------------------------------------------------
__global__ __launch_bounds__(256) void pool_kernel(const float* __restrict__ x,
                                                   float* __restrict__ p0,
                                                   float* __restrict__ stats0) {
    int idx = blockIdx.x * 256 + threadIdx.x;
    int j = idx % KS;
    int i = (idx / KS) % KS;
    int bc = idx / KK;
    const float* src = x + (size_t)bc * HW + (i * PL) * WW + j * PL;
    float s = 0.f;
#pragma unroll
    for (int a = 0; a < PL; ++a) {
        float4 v0 = *(const float4*)(src + a * WW);
        float4 v1 = *(const float4*)(src + a * WW + 4);
        s += v0.x + v0.y + v0.z + v0.w + v1.x + v1.y + v1.z + v1.w;
    }
    float v = s * (1.f / 64.f);
    p0[idx] = v;

    float sv = v, sq = v * v;
#pragma unroll
    for (int o = 32; o > 0; o >>= 1) {
        sv += __shfl_down(sv, o, 64);
        sq += __shfl_down(sq, o, 64);
    }
    if ((threadIdx.x & 63) == 0) {
        int b = idx / CKK;          // uniform across the wave
        atomicAdd(&stats0[2 * b + 0], sv);
        atomicAdd(&stats0[2 * b + 1], sq);
    }
}

// ---------------------------------------------------------------------------
// Kernel 2: LN0 -> depthwise 7x7 conv on the 7x7 map -> raw out + LN1 stats.
// One block per (sample, 24-channel segment): 32*8 = 256 blocks.
// ---------------------------------------------------------------------------
#define SEG 8
#define CPB (CC / SEG)       // 24 channels per block
#define CELLS (CPB * KK)     // 1176

__global__ __launch_bounds__(256) void mid_kernel(
    const float* __restrict__ p0,
    const float* __restrict__ ln0w, const float* __restrict__ ln0b,
    const float* __restrict__ w0,
    const float* __restrict__ stats0,
    float* __restrict__ q1,          // raw conv output [B, C*49]
    float* __restrict__ stats1)
{
    __shared__ float sA[CELLS];
    __shared__ float red[8];
    int b   = blockIdx.x / SEG;
    int seg = blockIdx.x - b * SEG;
    int base  = b * CKK + seg * CELLS;   // into p0 / q1
    int pbase = seg * CELLS;             // into ln0w / ln0b / w0
    int tid = threadIdx.x;

    float s0  = stats0[2 * b + 0];
    float ss0 = stats0[2 * b + 1];
    float mean = s0 * (1.f / CKK);
    float rstd = rsqrtf(ss0 * (1.f / CKK) - mean * mean + 1e-5f);

    for (int i = tid; i < CELLS; i += 256)
        sA[i] = (p0[base + i] - mean) * rstd * ln0w[pbase + i] + ln0b[pbase + i];
    __syncthreads();

    float s2 = 0.f, ss2 = 0.f;
    for (int i = tid; i < CELLS; i += 256) {
        int cl = i / KK;
        int r  = i - cl * KK;
        int i0 = r / KS;
        int j0 = r - i0 * KS;
        const float* a  = sA + cl * KK;
        const float* wc = w0 + pbase + cl * KK;
        float acc = 0.f;
#pragma unroll
        for (int u = 0; u < KS; ++u) {
            int ii = i0 + u - 3;
            if (ii < 0 || ii >= KS) continue;
#pragma unroll
            for (int vv = 0; vv < KS; ++vv) {
                int jj = j0 + vv - 3;
                if (jj < 0 || jj >= KS) continue;
                acc += a[ii * KS + jj] * wc[u * KS + vv];
            }
        }
        q1[base + i] = acc;
        s2 += acc; ss2 += acc * acc;
    }

#pragma unroll
    for (int o = 32; o > 0; o >>= 1) {
        s2  += __shfl_down(s2, o, 64);
        ss2 += __shfl_down(ss2, o, 64);
    }
    if ((tid & 63) == 0) {
        red[(tid >> 6) * 2 + 0] = s2;
        red[(tid >> 6) * 2 + 1] = ss2;
    }
    __syncthreads();
    if (tid == 0) {
        float a = red[0] + red[2] + red[4] + red[6];
        float c = red[1] + red[3] + red[5] + red[7];
        atomicAdd(&stats1[2 * b + 0], a);
        atomicAdd(&stats1[2 * b + 1], c);
    }
}

// ---------------------------------------------------------------------------
// Kernel 3: LN1+ReLU (prologue) then per-(b,c) depthwise 7x7 SAME conv.
// Halo-padded, row-skewed LDS tile -> branch-free inner loop, b128 reads.
// 8 outputs/thread: 56 rows x 7 octs = 392 compute lanes.
// ---------------------------------------------------------------------------
#define TW 68            // 56 + 4 left pad + 8 right pad, skew: 68 mod 32 = 4
#define TH 62            // 56 + 3 top + 3 bottom
#define NT 448

__global__ __launch_bounds__(NT) void conv_kernel(
    const float* __restrict__ x,
    const float* __restrict__ q1, const float* __restrict__ stats1,
    const float* __restrict__ ln1w, const float* __restrict__ ln1b,
    float* __restrict__ out)
{
    __shared__ float tile[TH * TW];   // 16.9 KB
    __shared__ float kt[KK];
    int bc = blockIdx.x;
    int b  = bc / CC;
    int c  = bc - b * CC;
    int tid = threadIdx.x;

    if (tid < KK) {
        float s1  = stats1[2 * b + 0];
        float ss1 = stats1[2 * b + 1];
        float m1 = s1 * (1.f / CKK);
        float r1 = rsqrtf(ss1 * (1.f / CKK) - m1 * m1 + 1e-5f);
        float v = (q1[(size_t)bc * KK + tid] - m1) * r1 * ln1w[c * KK + tid]
                  + ln1b[c * KK + tid];
        kt[tid] = v > 0.f ? v : 0.f;
    }

    // zero the whole tile (halo included), then load the interior
    for (int i = tid; i < TH * TW / 4; i += NT)
        ((float4*)tile)[i] = make_float4(0.f, 0.f, 0.f, 0.f);
    __syncthreads();
    const float* src = x + (size_t)bc * HW;
    for (int i = tid; i < HH * (WW / 4); i += NT) {
        int r = i / (WW / 4);
        int q = i - r * (WW / 4);
        *(float4*)(tile + (r + 3) * TW + 4 + q * 4) =
            *(const float4*)(src + r * WW + q * 4);
    }
    __syncthreads();

    float tp[KK];
#pragma unroll
    for (int t = 0; t < KK; ++t) tp[t] = kt[t];

    if (tid < 392) {
        int h  = tid / 7;              // output row 0..55
        int oc = (tid - h * 7) * 8;    // output col base 0,8,...,48
        float acc[8];
#pragma unroll
        for (int o = 0; o < 8; ++o) acc[o] = 0.f;

        const float* tb = tile + h * TW + oc;  // tile row h+u, col offset oc
#pragma unroll
        for (int u = 0; u < KS; ++u) {
            const float* rw = tb + u * TW;     // 16B-aligned (272B row stride)
            float w[16];
            *(float4*)(w + 0)  = *(const float4*)(rw + 0);
            *(float4*)(w + 4)  = *(const float4*)(rw + 4);
            *(float4*)(w + 8)  = *(const float4*)(rw + 8);
            *(float4*)(w + 12) = *(const float4*)(rw + 12);
#pragma unroll
            for (int v = 0; v < KS; ++v) {
                float kv = tp[u * KS + v];
#pragma unroll
                for (int o = 0; o < 8; ++o)
                    acc[o] += w[o + v + 1] * kv;   // tile col = oc+o+v+1
            }
        }
        float* dst = out + (size_t)bc * HW + h * WW + oc;
        *(float4*)(dst + 0) = make_float4(acc[0], acc[1], acc[2], acc[3]);
        *(float4*)(dst + 4) = make_float4(acc[4], acc[5], acc[6], acc[7]);
    }
}

// ---------------------------------------------------------------------------
extern "C" void kernel_launch(void* const* d_in, const int* in_sizes, int n_in,
                              void* d_out, int out_size, void* d_ws, size_t ws_size,
                              hipStream_t stream) {
    const float* x    = (const float*)d_in[0];
    const float* ln0w = (const float*)d_in[1];
    const float* ln0b = (const float*)d_in[2];
    const float* w0   = (const float*)d_in[3];
    const float* ln1w = (const float*)d_in[4];
    const float* ln1b = (const float*)d_in[5];
    float* out = (float*)d_out;

    float* p0    = (float*)d_ws;      // [NCELL] pooled
    float* q1    = p0 + NCELL;        // [NCELL] raw mid-conv output
    float* stats = q1 + NCELL;        // [128]: stats0 = [0..63], stats1 = [64..127]

    hipMemsetAsync(stats, 0, 128 * sizeof(float), stream);
    pool_kernel<<<NCELL / 256, 256, 0, stream>>>(x, p0, stats);
    mid_kernel<<<BB * SEG, 256, 0, stream>>>(p0, ln0w, ln0b, w0, stats, q1, stats + 64);
    conv_kernel<<<NBC, NT, 0, stream>>>(x, q1, stats + 64, ln1w, ln1b, out);
}

// Round 3
// 128.833 us; speedup vs baseline: 1.5736x; 1.5736x over previous
//
#include <hip/hip_runtime.h>

// Problem constants (B,C,H,W,K) = (32,192,56,56,7)
#define BB 32
#define CC 192
#define HH 56
#define WW 56
#define KS 7
#define HW 3136        // 56*56
#define KK 49
#define CKK 9408       // C*K*K
#define PL 8
#define NCELL (BB * CC * KK)   // 301056 = 1176*256
#define NBC (BB * CC)          // 6144
#define SPAD 32                // stats padding: one 128B line per sample

// ---------------------------------------------------------------------------
// K1: avg pool 56x56 -> 7x7. Pure streaming, no atomics.
// ---------------------------------------------------------------------------
__global__ __launch_bounds__(256) void pool_kernel(const float* __restrict__ x,
                                                   float* __restrict__ p0) {
    int idx = blockIdx.x * 256 + threadIdx.x;
    int j = idx % KS;
    int i = (idx / KS) % KS;
    int bc = idx / KK;
    const float* src = x + (size_t)bc * HW + (i * PL) * WW + j * PL;
    float s = 0.f;
#pragma unroll
    for (int a = 0; a < PL; ++a) {
        float4 v0 = *(const float4*)(src + a * WW);
        float4 v1 = *(const float4*)(src + a * WW + 4);
        s += v0.x + v0.y + v0.z + v0.w + v1.x + v1.y + v1.z + v1.w;
    }
    p0[idx] = s * (1.f / 64.f);
}

// ---------------------------------------------------------------------------
// K2: LN0 stats. Block t reduces p0[t*1176 .. +1176) (8 blocks per sample,
// blocks never straddle samples: 1176*8 = 9408). Padded fire-and-forget atomics.
// ---------------------------------------------------------------------------
__global__ __launch_bounds__(256) void stats0_kernel(const float* __restrict__ p0,
                                                     float* __restrict__ stats0) {
    __shared__ float red[8];
    int t = blockIdx.x;
    int b = t >> 3;
    const float* src = p0 + t * 1176;
    float s = 0.f, ss = 0.f;
    for (int i = threadIdx.x; i < 1176; i += 256) {
        float v = src[i];
        s += v; ss += v * v;
    }
#pragma unroll
    for (int o = 32; o > 0; o >>= 1) {
        s  += __shfl_down(s, o, 64);
        ss += __shfl_down(ss, o, 64);
    }
    if ((threadIdx.x & 63) == 0) {
        red[(threadIdx.x >> 6) * 2 + 0] = s;
        red[(threadIdx.x >> 6) * 2 + 1] = ss;
    }
    __syncthreads();
    if (threadIdx.x == 0) {
        atomicAdd(&stats0[b * SPAD + 0], red[0] + red[2] + red[4] + red[6]);
        atomicAdd(&stats0[b * SPAD + 1], red[1] + red[3] + red[5] + red[7]);
    }
}

// ---------------------------------------------------------------------------
// K3: LN0-normalize + depthwise 7x7 conv on the 7x7 map, one WAVE per (b,c).
// The 49 cells live one-per-lane; conv taps come via __shfl. Branch-free.
// Also accumulates LN1 stats (padded atomics, 2 per wave).
// ---------------------------------------------------------------------------
__global__ __launch_bounds__(512) void mid_kernel(
    const float* __restrict__ p0,
    const float* __restrict__ ln0w, const float* __restrict__ ln0b,
    const float* __restrict__ w0,
    const float* __restrict__ stats0,
    float* __restrict__ q1,
    float* __restrict__ stats1)
{
    int tid  = threadIdx.x;
    int lane = tid & 63;
    int bc   = blockIdx.x * 8 + (tid >> 6);
    int b = bc / CC;
    int c = bc - b * CC;

    float s0   = stats0[b * SPAD + 0];
    float ss0  = stats0[b * SPAD + 1];
    float mean = s0 * (1.f / CKK);
    float rstd = rsqrtf(ss0 * (1.f / CKK) - mean * mean + 1e-5f);

    float val = 0.f;
    if (lane < KK)
        val = (p0[bc * KK + lane] - mean) * rstd * ln0w[c * KK + lane]
              + ln0b[c * KK + lane];

    int i0 = lane / KS;          // garbage for lane>=49, masked below
    int j0 = lane - i0 * KS;
    const float* wc = w0 + c * KK;   // uniform -> scalar loads

    float acc = 0.f;
#pragma unroll
    for (int u = 0; u < KS; ++u) {
        int ii = i0 + u - 3;
#pragma unroll
        for (int v = 0; v < KS; ++v) {
            int jj = j0 + v - 3;
            bool ok = (ii >= 0) && (ii < KS) && (jj >= 0) && (jj < KS);
            int sl = ok ? (ii * KS + jj) : 0;
            float sv = __shfl(val, sl, 64);
            acc += ok ? sv * wc[u * KS + v] : 0.f;
        }
    }
    if (lane >= KK) acc = 0.f;
    if (lane < KK) q1[bc * KK + lane] = acc;

    float s2 = acc, ss2 = acc * acc;
#pragma unroll
    for (int o = 32; o > 0; o >>= 1) {
        s2  += __shfl_down(s2, o, 64);
        ss2 += __shfl_down(ss2, o, 64);
    }
    if (lane == 0) {
        atomicAdd(&stats1[b * SPAD + 0], s2);
        atomicAdd(&stats1[b * SPAD + 1], ss2);
    }
}

// ---------------------------------------------------------------------------
// K4: LN1 + ReLU -> dynamic kernels (elementwise, 2.4 MB)
// ---------------------------------------------------------------------------
__global__ __launch_bounds__(256) void lnrelu_kernel(
    const float* __restrict__ q1, const float* __restrict__ stats1,
    const float* __restrict__ ln1w, const float* __restrict__ ln1b,
    float* __restrict__ ker)
{
    int idx = blockIdx.x * 256 + threadIdx.x;   // NCELL = 1176*256 exact
    int bc = idx / KK;
    int t  = idx - bc * KK;
    int b  = bc / CC;
    int c  = bc - b * CC;
    float s1 = stats1[b * SPAD + 0];
    float q  = stats1[b * SPAD + 1];
    float m  = s1 * (1.f / CKK);
    float r  = rsqrtf(q * (1.f / CKK) - m * m + 1e-5f);
    float v  = (q1[idx] - m) * r * ln1w[c * KK + t] + ln1b[c * KK + t];
    ker[idx] = v > 0.f ? v : 0.f;
}

// ---------------------------------------------------------------------------
// K5: per-(b,c) depthwise 7x7 SAME conv, NO LDS. One block per (b,c),
// 8 waves x 7 output rows; lane l owns column l. 7x7 register shift-window.
// Taps pinned to SGPRs via readfirstlane (v_fmac takes one SGPR operand).
// ---------------------------------------------------------------------------
__device__ __forceinline__ float rfl(float v) {
    return __int_as_float(__builtin_amdgcn_readfirstlane(__float_as_int(v)));
}

__global__ __launch_bounds__(512) void conv_kernel(const float* __restrict__ x,
                                                   const float* __restrict__ ker,
                                                   float* __restrict__ out) {
    int bc   = blockIdx.x;
    int lane = threadIdx.x & 63;
    int r0   = (threadIdx.x >> 6) * 7;          // strip: 7 output rows per wave
    const float* xb = x + (size_t)bc * HW;
    float* ob = out + (size_t)bc * HW;

    const float* kp = ker + (size_t)bc * KK;    // uniform per block
    float tap[KK];
#pragma unroll
    for (int t = 0; t < KK; ++t) tap[t] = rfl(kp[t]);

    // per-lane clamped column offsets + 0/1 masks (row-independent)
    int coff[KS];
    float fm[KS];
#pragma unroll
    for (int dv = 0; dv < KS; ++dv) {
        int col = lane - 3 + dv;
        int cl  = col < 0 ? 0 : (col > 55 ? 55 : col);
        coff[dv] = cl;
        fm[dv]   = (col >= 0 && col < WW) ? 1.f : 0.f;
    }

    float win[7][KS];
    // init: input rows r0-3 .. r0+2 -> slots 0..5
#pragma unroll
    for (int k = 0; k < 6; ++k) {
        int ir = r0 - 3 + k;
        if (ir >= 0 && ir < HH) {
            const float* rp = xb + ir * WW;
#pragma unroll
            for (int dv = 0; dv < KS; ++dv) win[k][dv] = rp[coff[dv]] * fm[dv];
        } else {
#pragma unroll
            for (int dv = 0; dv < KS; ++dv) win[k][dv] = 0.f;
        }
    }

#pragma unroll
    for (int r = 0; r < 7; ++r) {
        int ir = r0 + r + 3;                 // new bottom row
        int sl = (6 + r) % 7;                // static after unroll
        if (ir < HH) {
            const float* rp = xb + ir * WW;
#pragma unroll
            for (int dv = 0; dv < KS; ++dv) win[sl][dv] = rp[coff[dv]] * fm[dv];
        } else {
#pragma unroll
            for (int dv = 0; dv < KS; ++dv) win[sl][dv] = 0.f;
        }
        float acc = 0.f;
#pragma unroll
        for (int u = 0; u < KS; ++u) {
#pragma unroll
            for (int dv = 0; dv < KS; ++dv)
                acc = fmaf(win[(r + u) % 7][dv], tap[u * KS + dv], acc);
        }
        if (lane < WW) ob[(r0 + r) * WW + lane] = acc;
    }
}

// ---------------------------------------------------------------------------
extern "C" void kernel_launch(void* const* d_in, const int* in_sizes, int n_in,
                              void* d_out, int out_size, void* d_ws, size_t ws_size,
                              hipStream_t stream) {
    const float* x    = (const float*)d_in[0];
    const float* ln0w = (const float*)d_in[1];
    const float* ln0b = (const float*)d_in[2];
    const float* w0   = (const float*)d_in[3];
    const float* ln1w = (const float*)d_in[4];
    const float* ln1b = (const float*)d_in[5];
    float* out = (float*)d_out;

    float* p0     = (float*)d_ws;          // [NCELL]
    float* q1     = p0 + NCELL;            // [NCELL]
    float* ker    = q1 + NCELL;            // [NCELL]
    float* stats0 = ker + NCELL;           // [BB*SPAD]
    float* stats1 = stats0 + BB * SPAD;    // [BB*SPAD]

    hipMemsetAsync(stats0, 0, 2 * BB * SPAD * sizeof(float), stream);
    pool_kernel  <<<NCELL / 256, 256, 0, stream>>>(x, p0);
    stats0_kernel<<<BB * 8, 256, 0, stream>>>(p0, stats0);
    mid_kernel   <<<NBC / 8, 512, 0, stream>>>(p0, ln0w, ln0b, w0, stats0, q1, stats1);
    lnrelu_kernel<<<NCELL / 256, 256, 0, stream>>>(q1, stats1, ln1w, ln1b, ker);
    conv_kernel  <<<NBC, 512, 0, stream>>>(x, ker, out);
}

// Round 4
// 91.230 us; speedup vs baseline: 2.2221x; 1.4122x over previous
//
#include <hip/hip_runtime.h>

// Problem constants (B,C,H,W,K) = (32,192,56,56,7)
#define BB 32
#define CC 192
#define HH 56
#define WW 56
#define KS 7
#define HW 3136        // 56*56
#define KK 49
#define CKK 9408       // C*K*K
#define PL 8
#define NCELL (BB * CC * KK)   // 301056 = 1176*256
#define NBC (BB * CC)          // 6144
#define SPAD 32                // stats padding: one 128B line per sample

// ---------------------------------------------------------------------------
// K1: avg pool 56x56 -> 7x7. Pure streaming, no atomics.
// ---------------------------------------------------------------------------
__global__ __launch_bounds__(256) void pool_kernel(const float* __restrict__ x,
                                                   float* __restrict__ p0) {
    int idx = blockIdx.x * 256 + threadIdx.x;
    int j = idx % KS;
    int i = (idx / KS) % KS;
    int bc = idx / KK;
    const float* src = x + (size_t)bc * HW + (i * PL) * WW + j * PL;
    float s = 0.f;
#pragma unroll
    for (int a = 0; a < PL; ++a) {
        float4 v0 = *(const float4*)(src + a * WW);
        float4 v1 = *(const float4*)(src + a * WW + 4);
        s += v0.x + v0.y + v0.z + v0.w + v1.x + v1.y + v1.z + v1.w;
    }
    p0[idx] = s * (1.f / 64.f);
}

// ---------------------------------------------------------------------------
// K2: LN0 stats. Block t reduces p0[t*1176 .. +1176); 8 blocks per sample.
// ---------------------------------------------------------------------------
__global__ __launch_bounds__(256) void stats0_kernel(const float* __restrict__ p0,
                                                     float* __restrict__ stats0) {
    __shared__ float red[8];
    int t = blockIdx.x;
    int b = t >> 3;
    const float* src = p0 + t * 1176;
    float s = 0.f, ss = 0.f;
    for (int i = threadIdx.x; i < 1176; i += 256) {
        float v = src[i];
        s += v; ss += v * v;
    }
#pragma unroll
    for (int o = 32; o > 0; o >>= 1) {
        s  += __shfl_down(s, o, 64);
        ss += __shfl_down(ss, o, 64);
    }
    if ((threadIdx.x & 63) == 0) {
        red[(threadIdx.x >> 6) * 2 + 0] = s;
        red[(threadIdx.x >> 6) * 2 + 1] = ss;
    }
    __syncthreads();
    if (threadIdx.x == 0) {
        atomicAdd(&stats0[b * SPAD + 0], red[0] + red[2] + red[4] + red[6]);
        atomicAdd(&stats0[b * SPAD + 1], red[1] + red[3] + red[5] + red[7]);
    }
}

// ---------------------------------------------------------------------------
// K3: LN0-normalize + depthwise 7x7 conv on the 7x7 map, one WAVE per (b,c).
// ---------------------------------------------------------------------------
__global__ __launch_bounds__(512) void mid_kernel(
    const float* __restrict__ p0,
    const float* __restrict__ ln0w, const float* __restrict__ ln0b,
    const float* __restrict__ w0,
    const float* __restrict__ stats0,
    float* __restrict__ q1,
    float* __restrict__ stats1)
{
    int tid  = threadIdx.x;
    int lane = tid & 63;
    int bc   = blockIdx.x * 8 + (tid >> 6);
    int b = bc / CC;
    int c = bc - b * CC;

    float s0   = stats0[b * SPAD + 0];
    float ss0  = stats0[b * SPAD + 1];
    float mean = s0 * (1.f / CKK);
    float rstd = rsqrtf(ss0 * (1.f / CKK) - mean * mean + 1e-5f);

    float val = 0.f;
    if (lane < KK)
        val = (p0[bc * KK + lane] - mean) * rstd * ln0w[c * KK + lane]
              + ln0b[c * KK + lane];

    int i0 = lane / KS;
    int j0 = lane - i0 * KS;
    const float* wc = w0 + c * KK;

    float acc = 0.f;
#pragma unroll
    for (int u = 0; u < KS; ++u) {
        int ii = i0 + u - 3;
#pragma unroll
        for (int v = 0; v < KS; ++v) {
            int jj = j0 + v - 3;
            bool ok = (ii >= 0) && (ii < KS) && (jj >= 0) && (jj < KS);
            int sl = ok ? (ii * KS + jj) : 0;
            float sv = __shfl(val, sl, 64);
            acc += ok ? sv * wc[u * KS + v] : 0.f;
        }
    }
    if (lane >= KK) acc = 0.f;
    if (lane < KK) q1[bc * KK + lane] = acc;

    float s2 = acc, ss2 = acc * acc;
#pragma unroll
    for (int o = 32; o > 0; o >>= 1) {
        s2  += __shfl_down(s2, o, 64);
        ss2 += __shfl_down(ss2, o, 64);
    }
    if (lane == 0) {
        atomicAdd(&stats1[b * SPAD + 0], s2);
        atomicAdd(&stats1[b * SPAD + 1], ss2);
    }
}

// ---------------------------------------------------------------------------
// K4: LN1 + ReLU -> dynamic kernels
// ---------------------------------------------------------------------------
__global__ __launch_bounds__(256) void lnrelu_kernel(
    const float* __restrict__ q1, const float* __restrict__ stats1,
    const float* __restrict__ ln1w, const float* __restrict__ ln1b,
    float* __restrict__ ker)
{
    int idx = blockIdx.x * 256 + threadIdx.x;
    int bc = idx / KK;
    int t  = idx - bc * KK;
    int b  = bc / CC;
    int c  = bc - b * CC;
    float s1 = stats1[b * SPAD + 0];
    float q  = stats1[b * SPAD + 1];
    float m  = s1 * (1.f / CKK);
    float r  = rsqrtf(q * (1.f / CKK) - m * m + 1e-5f);
    float v  = (q1[idx] - m) * r * ln1w[c * KK + t] + ln1b[c * KK + t];
    ker[idx] = v > 0.f ? v : 0.f;
}

// ---------------------------------------------------------------------------
// K5: per-(b,c) depthwise 7x7 SAME conv — accumulator-forwarding version.
// One block per (b,c); 4 waves x 14 output rows; lane l owns column l.
// Single pass over 20 input rows; each row's 7 per-lane taps are forwarded
// into the output-row accumulators that need them. No register window, no
// modular indexing -> no spills; 7-14 independent fmac chains for ILP.
// ---------------------------------------------------------------------------
#define NWV 4
#define NR 14            // output rows per wave (4*14 = 56)

__device__ __forceinline__ float rfl(float v) {
    return __int_as_float(__builtin_amdgcn_readfirstlane(__float_as_int(v)));
}

__global__ __launch_bounds__(NWV * 64) void conv_kernel(
    const float* __restrict__ x,
    const float* __restrict__ ker,
    float* __restrict__ out)
{
    int bc   = blockIdx.x;
    int lane = threadIdx.x & 63;
    int wid  = threadIdx.x >> 6;
    int r0   = wid * NR;
    const float* xb = x + (size_t)bc * HW;
    float* ob = out + (size_t)bc * HW;

    const float* kp = ker + (size_t)bc * KK;   // uniform -> scalar loads
    float tap[KK];
#pragma unroll
    for (int t = 0; t < KK; ++t) tap[t] = rfl(kp[t]);

    // per-lane clamped column offsets + 0/1 masks (row-independent)
    int coff[KS];
    float fm[KS];
#pragma unroll
    for (int dv = 0; dv < KS; ++dv) {
        int col = lane - 3 + dv;
        coff[dv] = col < 0 ? 0 : (col > 55 ? 55 : col);
        fm[dv]   = (col >= 0 && col < WW) ? 1.f : 0.f;
    }

    float acc[NR];
#pragma unroll
    for (int o = 0; o < NR; ++o) acc[o] = 0.f;

#pragma unroll
    for (int k = 0; k < NR + 6; ++k) {
        int ir = r0 - 3 + k;                 // wave-uniform row index
        if (ir >= 0 && ir < HH) {            // scalar branch, no divergence
            const float* rp = xb + ir * WW;
            float v[KS];
#pragma unroll
            for (int dv = 0; dv < KS; ++dv)
                v[dv] = rp[coff[dv]] * fm[dv];
#pragma unroll
            for (int u = 0; u < KS; ++u) {
                int o = k - u;               // static after unroll
                if (o >= 0 && o < NR) {
#pragma unroll
                    for (int dv = 0; dv < KS; ++dv)
                        acc[o] = fmaf(v[dv], tap[u * KS + dv], acc[o]);
                }
            }
        }
    }

    if (lane < WW) {
#pragma unroll
        for (int o = 0; o < NR; ++o)
            ob[(r0 + o) * WW + lane] = acc[o];
    }
}

// ---------------------------------------------------------------------------
extern "C" void kernel_launch(void* const* d_in, const int* in_sizes, int n_in,
                              void* d_out, int out_size, void* d_ws, size_t ws_size,
                              hipStream_t stream) {
    const float* x    = (const float*)d_in[0];
    const float* ln0w = (const float*)d_in[1];
    const float* ln0b = (const float*)d_in[2];
    const float* w0   = (const float*)d_in[3];
    const float* ln1w = (const float*)d_in[4];
    const float* ln1b = (const float*)d_in[5];
    float* out = (float*)d_out;

    float* p0     = (float*)d_ws;          // [NCELL]
    float* q1     = p0 + NCELL;            // [NCELL]
    float* ker    = q1 + NCELL;            // [NCELL]
    float* stats0 = ker + NCELL;           // [BB*SPAD]
    float* stats1 = stats0 + BB * SPAD;    // [BB*SPAD]

    hipMemsetAsync(stats0, 0, 2 * BB * SPAD * sizeof(float), stream);
    pool_kernel  <<<NCELL / 256, 256, 0, stream>>>(x, p0);
    stats0_kernel<<<BB * 8, 256, 0, stream>>>(p0, stats0);
    mid_kernel   <<<NBC / 8, 512, 0, stream>>>(p0, ln0w, ln0b, w0, stats0, q1, stats1);
    lnrelu_kernel<<<NCELL / 256, 256, 0, stream>>>(q1, stats1, ln1w, ln1b, ker);
    conv_kernel  <<<NBC, NWV * 64, 0, stream>>>(x, ker, out);
}

// Round 5
// 82.879 us; speedup vs baseline: 2.4461x; 1.1008x over previous
//
#include <hip/hip_runtime.h>

// Problem constants (B,C,H,W,K) = (32,192,56,56,7)
#define BB 32
#define CC 192
#define HH 56
#define WW 56
#define KS 7
#define HW 3136        // 56*56
#define KK 49
#define CKK 9408       // C*K*K
#define PL 8
#define NCELL (BB * CC * KK)   // 301056 = 1176*256
#define NBC (BB * CC)          // 6144
#define SPAD 32                // stats padding: one 128B line per sample

// ---------------------------------------------------------------------------
// K1: avg pool 56x56 -> 7x7. Pure streaming, no atomics.
// ---------------------------------------------------------------------------
__global__ __launch_bounds__(256) void pool_kernel(const float* __restrict__ x,
                                                   float* __restrict__ p0) {
    int idx = blockIdx.x * 256 + threadIdx.x;
    int j = idx % KS;
    int i = (idx / KS) % KS;
    int bc = idx / KK;
    const float* src = x + (size_t)bc * HW + (i * PL) * WW + j * PL;
    float s = 0.f;
#pragma unroll
    for (int a = 0; a < PL; ++a) {
        float4 v0 = *(const float4*)(src + a * WW);
        float4 v1 = *(const float4*)(src + a * WW + 4);
        s += v0.x + v0.y + v0.z + v0.w + v1.x + v1.y + v1.z + v1.w;
    }
    p0[idx] = s * (1.f / 64.f);
}

// ---------------------------------------------------------------------------
// K2: LN0 stats. Block t reduces p0[t*1176 .. +1176); 8 blocks per sample.
// ---------------------------------------------------------------------------
__global__ __launch_bounds__(256) void stats0_kernel(const float* __restrict__ p0,
                                                     float* __restrict__ stats0) {
    __shared__ float red[8];
    int t = blockIdx.x;
    int b = t >> 3;
    const float* src = p0 + t * 1176;
    float s = 0.f, ss = 0.f;
    for (int i = threadIdx.x; i < 1176; i += 256) {
        float v = src[i];
        s += v; ss += v * v;
    }
#pragma unroll
    for (int o = 32; o > 0; o >>= 1) {
        s  += __shfl_down(s, o, 64);
        ss += __shfl_down(ss, o, 64);
    }
    if ((threadIdx.x & 63) == 0) {
        red[(threadIdx.x >> 6) * 2 + 0] = s;
        red[(threadIdx.x >> 6) * 2 + 1] = ss;
    }
    __syncthreads();
    if (threadIdx.x == 0) {
        atomicAdd(&stats0[b * SPAD + 0], red[0] + red[2] + red[4] + red[6]);
        atomicAdd(&stats0[b * SPAD + 1], red[1] + red[3] + red[5] + red[7]);
    }
}

// ---------------------------------------------------------------------------
// K3: LN0-normalize + depthwise 7x7 conv on the 7x7 map, one WAVE per (b,c).
// Produces raw conv output q1 + LN1 stats (padded atomics).
// ---------------------------------------------------------------------------
__global__ __launch_bounds__(512) void mid_kernel(
    const float* __restrict__ p0,
    const float* __restrict__ ln0w, const float* __restrict__ ln0b,
    const float* __restrict__ w0,
    const float* __restrict__ stats0,
    float* __restrict__ q1,
    float* __restrict__ stats1)
{
    int tid  = threadIdx.x;
    int lane = tid & 63;
    int bc   = blockIdx.x * 8 + (tid >> 6);
    int b = bc / CC;
    int c = bc - b * CC;

    float s0   = stats0[b * SPAD + 0];
    float ss0  = stats0[b * SPAD + 1];
    float mean = s0 * (1.f / CKK);
    float rstd = rsqrtf(ss0 * (1.f / CKK) - mean * mean + 1e-5f);

    float val = 0.f;
    if (lane < KK)
        val = (p0[bc * KK + lane] - mean) * rstd * ln0w[c * KK + lane]
              + ln0b[c * KK + lane];

    int i0 = lane / KS;
    int j0 = lane - i0 * KS;
    const float* wc = w0 + c * KK;

    float acc = 0.f;
#pragma unroll
    for (int u = 0; u < KS; ++u) {
        int ii = i0 + u - 3;
#pragma unroll
        for (int v = 0; v < KS; ++v) {
            int jj = j0 + v - 3;
            bool ok = (ii >= 0) && (ii < KS) && (jj >= 0) && (jj < KS);
            int sl = ok ? (ii * KS + jj) : 0;
            float sv = __shfl(val, sl, 64);
            acc += ok ? sv * wc[u * KS + v] : 0.f;
        }
    }
    if (lane >= KK) acc = 0.f;
    if (lane < KK) q1[bc * KK + lane] = acc;

    float s2 = acc, ss2 = acc * acc;
#pragma unroll
    for (int o = 32; o > 0; o >>= 1) {
        s2  += __shfl_down(s2, o, 64);
        ss2 += __shfl_down(ss2, o, 64);
    }
    if (lane == 0) {
        atomicAdd(&stats1[b * SPAD + 0], s2);
        atomicAdd(&stats1[b * SPAD + 1], ss2);
    }
}

// ---------------------------------------------------------------------------
// K4: fused LN1+ReLU tap computation + per-(b,c) depthwise 7x7 SAME conv.
// Zero-halo LDS tile [62][64]; main loop = 140 ds_read_b32 (imm offsets off
// one base VGPR) + 686 v_fmac (taps in SGPR). No masks, no addressing VALU.
// 4 waves x 14 output rows; lane l owns output column l (lanes 56-63 idle).
// ---------------------------------------------------------------------------
#define TILEW 64
#define TILEH 62

__device__ __forceinline__ float rfl(float v) {
    return __int_as_float(__builtin_amdgcn_readfirstlane(__float_as_int(v)));
}

__global__ __launch_bounds__(256) void conv_kernel(
    const float* __restrict__ x,
    const float* __restrict__ q1, const float* __restrict__ stats1,
    const float* __restrict__ ln1w, const float* __restrict__ ln1b,
    float* __restrict__ out)
{
    __shared__ float tile[TILEH * TILEW];   // 15.5 KB, tile[r][c] = x[r-3][c-4]
    __shared__ float kt[KK];
    int bc   = blockIdx.x;
    int b    = bc / CC;
    int c    = bc - b * CC;
    int tid  = threadIdx.x;
    int lane = tid & 63;
    int wid  = tid >> 6;

    // ---- taps: LN1 + ReLU on q1 (fused, replaces lnrelu kernel) ----
    if (tid < KK) {
        float s1  = stats1[b * SPAD + 0];
        float ss1 = stats1[b * SPAD + 1];
        float m = s1 * (1.f / CKK);
        float r = rsqrtf(ss1 * (1.f / CKK) - m * m + 1e-5f);
        float v = (q1[(size_t)bc * KK + tid] - m) * r * ln1w[c * KK + tid]
                  + ln1b[c * KK + tid];
        kt[tid] = v > 0.f ? v : 0.f;
    }

    // ---- zero halo: rows 0-2 & 59-61 full width; cols 0-3 & 60-63 ----
    if (tid < 96) {
        int r = tid >> 4;                  // 0..5
        int q = tid & 15;                  // 16 float4 per row
        int row = r < 3 ? r : 56 + r;      // 0,1,2,59,60,61
        *(float4*)(tile + row * TILEW + q * 4) = make_float4(0.f, 0.f, 0.f, 0.f);
    } else if (tid < 152) {
        *(float4*)(tile + (tid - 96 + 3) * TILEW) = make_float4(0.f, 0.f, 0.f, 0.f);
    } else if (tid < 208) {
        *(float4*)(tile + (tid - 152 + 3) * TILEW + 60) = make_float4(0.f, 0.f, 0.f, 0.f);
    }

    // ---- stage interior: x[r][0..55] -> tile[r+3][4..59] (16B aligned) ----
    const float* src = x + (size_t)bc * HW;
    for (int i = tid; i < HH * 14; i += 256) {
        int r = i / 14;
        int q = i - r * 14;
        *(float4*)(tile + (r + 3) * TILEW + 4 + q * 4) =
            *(const float4*)(src + r * WW + q * 4);
    }
    __syncthreads();

    // ---- taps -> SGPRs ----
    float tap[KK];
#pragma unroll
    for (int t = 0; t < KK; ++t) tap[t] = rfl(kt[t]);

    // ---- main loop: single pass over 20 tile rows, accumulator forwarding ----
    int r0 = wid * 14;
    const float* trow = tile + r0 * TILEW + lane + 1;  // one base VGPR
    float acc[14];
#pragma unroll
    for (int o = 0; o < 14; ++o) acc[o] = 0.f;

#pragma unroll
    for (int k = 0; k < 20; ++k) {
        float v[KS];
#pragma unroll
        for (int dv = 0; dv < KS; ++dv)
            v[dv] = trow[k * TILEW + dv];            // ds_read_b32, imm offset
#pragma unroll
        for (int u = 0; u < KS; ++u) {
            int o = k - u;                           // static after unroll
            if (o >= 0 && o < 14) {
#pragma unroll
                for (int dv = 0; dv < KS; ++dv)
                    acc[o] = fmaf(v[dv], tap[u * KS + dv], acc[o]);
            }
        }
    }

    float* ob = out + (size_t)bc * HW;
    if (lane < WW) {
#pragma unroll
        for (int o = 0; o < 14; ++o)
            ob[(r0 + o) * WW + lane] = acc[o];
    }
}

// ---------------------------------------------------------------------------
extern "C" void kernel_launch(void* const* d_in, const int* in_sizes, int n_in,
                              void* d_out, int out_size, void* d_ws, size_t ws_size,
                              hipStream_t stream) {
    const float* x    = (const float*)d_in[0];
    const float* ln0w = (const float*)d_in[1];
    const float* ln0b = (const float*)d_in[2];
    const float* w0   = (const float*)d_in[3];
    const float* ln1w = (const float*)d_in[4];
    const float* ln1b = (const float*)d_in[5];
    float* out = (float*)d_out;

    float* p0     = (float*)d_ws;          // [NCELL]
    float* q1     = p0 + NCELL;            // [NCELL]
    float* stats0 = q1 + NCELL;            // [BB*SPAD]
    float* stats1 = stats0 + BB * SPAD;    // [BB*SPAD]

    hipMemsetAsync(stats0, 0, 2 * BB * SPAD * sizeof(float), stream);
    pool_kernel  <<<NCELL / 256, 256, 0, stream>>>(x, p0);
    stats0_kernel<<<BB * 8, 256, 0, stream>>>(p0, stats0);
    mid_kernel   <<<NBC / 8, 512, 0, stream>>>(p0, ln0w, ln0b, w0, stats0, q1, stats1);
    conv_kernel  <<<NBC, 256, 0, stream>>>(x, q1, stats1, ln1w, ln1b, out);
}